// Round 3
// baseline (236.172 us; speedup 1.0000x reference)
//
#include <hip/hip_runtime.h>
#include <math.h>

// Match numpy's separate mul/add roundings — no implicit FMA contraction.
// (Explicit __builtin_fmaf below is intentional and unaffected.)
#pragma clang fp contract(off)

#define TPB 256
#define ROWLEN 1024
#define PERSIST_BLOCKS 2048   // 4 waves/block -> 8192 row-waves, 4 rows each

// Native clang vector type (required by __builtin_nontemporal_store).
typedef float f32x4 __attribute__((ext_vector_type(4)));

// Uniform-value SGPR hoist (value identical across lanes by construction).
static __device__ __forceinline__ float bcast_f32(float v) {
    return __int_as_float(__builtin_amdgcn_readfirstlane(__float_as_int(v)));
}

// ---- DPP wave64 reductions (VALU-only; no LDS pipe, no barriers) ----
__device__ __forceinline__ float wave_max_dpp(float m) {
    const int NEG_INF = 0xff800000;             // -inf bits (fmax identity)
    int v;
    v = __builtin_amdgcn_update_dpp(NEG_INF, __float_as_int(m), 0x111, 0xf, 0xf, false);
    m = fmaxf(m, __int_as_float(v));
    v = __builtin_amdgcn_update_dpp(NEG_INF, __float_as_int(m), 0x112, 0xf, 0xf, false);
    m = fmaxf(m, __int_as_float(v));
    v = __builtin_amdgcn_update_dpp(NEG_INF, __float_as_int(m), 0x114, 0xf, 0xf, false);
    m = fmaxf(m, __int_as_float(v));
    v = __builtin_amdgcn_update_dpp(NEG_INF, __float_as_int(m), 0x118, 0xf, 0xf, false);
    m = fmaxf(m, __int_as_float(v));
    v = __builtin_amdgcn_update_dpp(NEG_INF, __float_as_int(m), 0x142, 0xa, 0xf, false);
    m = fmaxf(m, __int_as_float(v));
    v = __builtin_amdgcn_update_dpp(NEG_INF, __float_as_int(m), 0x143, 0xc, 0xf, false);
    m = fmaxf(m, __int_as_float(v));
    return __int_as_float(__builtin_amdgcn_readlane(__float_as_int(m), 63));
}

__device__ __forceinline__ unsigned wave_sum_dpp_u32(unsigned a) {
    int v;
    v = __builtin_amdgcn_update_dpp(0, (int)a, 0x111, 0xf, 0xf, false); a += (unsigned)v;
    v = __builtin_amdgcn_update_dpp(0, (int)a, 0x112, 0xf, 0xf, false); a += (unsigned)v;
    v = __builtin_amdgcn_update_dpp(0, (int)a, 0x114, 0xf, 0xf, false); a += (unsigned)v;
    v = __builtin_amdgcn_update_dpp(0, (int)a, 0x118, 0xf, 0xf, false); a += (unsigned)v;
    v = __builtin_amdgcn_update_dpp(0, (int)a, 0x142, 0xa, 0xf, false); a += (unsigned)v;
    v = __builtin_amdgcn_update_dpp(0, (int)a, 0x143, 0xc, 0xf, false); a += (unsigned)v;
    return (unsigned)__builtin_amdgcn_readlane((int)a, 63);
}

// WAVE-per-row, persistent, zero-LDS / zero-barrier.
//
// R2 post-mortem: block-per-row (persistent+prefetch) stayed on the
// ~80us plateau with VALUBusy 49%, BW 2.5TB/s — instruction-issue
// bound, not latency bound. Per 256 elements it paid a full DPP max
// chain (12 dep VALU) + 2 DPP sum chains (24) + 2 barriers + LDS
// round-trips + a 4x-replicated f64 divide + per-row addressing.
//
// This shape: 1 wave owns a full row (16 elems/lane, 4x dwordx4).
// All per-row overhead (reduce chains, f64 div, addressing, epilogue
// constants) amortizes over 1024 elements instead of 256 (~1.5-1.7x
// fewer issued instructions/element), lane ILP is 16 not 4, and with
// no barriers any resident wave fills any stall slot. Uniform
// constants are readfirstlane-hoisted to SGPRs; __launch_bounds__
// (256,8) caps VGPR at 64 -> 8 waves/SIMD.
//
// Numerics: per-element math bit-identical to the verified 224us
// kernel (absmax 4.27e-4 family):
//  - 1/sf, b, c, x0 via double-float Newton (rh+rl ~ 2^-46 rel).
//  - x/sf: double-float multiply + exact-residual FMA ~= CR f32 division.
//  - exp_int: pure f32 mul/add/ldexp/floor — bit-identical to numpy.
//  - Row sum: per-lane u32 over 16 elems <= 16*3.66e7 < 2^30 (exact);
//    lo16 chain <= 64*65535 < 2^22, hi16 chain <= 64*2^14 = 2^20 (both
//    exact u32); total (hi<<16)+lo < 2^36 exact in f64, order-
//    independent => factor = floor(2^32/sum) exact (the catastrophic
//    flip stays impossible).
//  - Epilogue reciprocals f32-rounded: rare +-1 A-quantum flips,
//    3.9e-4 << 1.87e-3 threshold.
__global__ __launch_bounds__(TPB, 8) void qsplit_int_softmax_kernel(
    const float* __restrict__ x,
    const float* __restrict__ scale_p,
    const float* __restrict__ thr_p,
    float* __restrict__ out,
    const int rows)
{
    const int tid  = threadIdx.x;
    const int lane = tid & 63;
    const int wid  = tid >> 6;
    const int nw   = (int)(gridDim.x << 2);      // total row-waves
    int r = (int)(blockIdx.x << 2) | wid;        // this wave's first row

    const float sf  = scale_p[0];   // 0.05f
    const float thr = thr_p[0];     // 0.1f

    // ---- f32 preamble: double-float 1/sf (once per wave) ----
    const float rh = bcast_f32(1.0f / sf);                 // IEEE f32 div
    const float er = __builtin_fmaf(-sf, rh, 1.0f);        // residual
    const float rl = bcast_f32(rh * er);                   // rh+rl ~ 1/sf @2^-46

    // q = a/sf in double-float, then floor (margins: .137/.147/.845)
    #define DF_DIV(a) ({ float _p = (a) * rh; \
                         float _e = __builtin_fmaf((a), rh, -_p); \
                         _p + __builtin_fmaf((a), rl, _e); })
    const float x0f    = bcast_f32(floorf(DF_DIV(-0.69314718f)));    // -14
    const float bfc    = bcast_f32(floorf(DF_DIV(2.7073824f)));      // 54 (c1/c0)
    const float s2     = sf * sf;
    const float r2h    = 1.0f / s2;
    const float r2e    = __builtin_fmaf(-s2, r2h, 1.0f);
    const float r2l    = r2h * r2e;
    const float cq     = __builtin_fmaf(2.7921141f, r2l,
                         2.7921141f * r2h);                          // c2/c0/sf^2
    const float cfc    = bcast_f32(floorf(cq));                      // 1116
    const float clampf = bcast_f32(15.0f * x0f);                     // -210 exact
    const float invx0f = bcast_f32(1.0f / x0f);

    const float osA  = bcast_f32(thr / 255.0f);            // f32 div, as numpy
    const float osB  = bcast_f32(1.0f / 255.0f);
    const float invA = bcast_f32(1.0f / (4294967296.0f * osA)); // <=1ulp vs CR
    const float invB = bcast_f32(1.0f / (4294967296.0f * osB));
    const float thrq = bcast_f32(floorf(thr * 256.0f));    // 25

    if (r >= rows) return;

    const size_t step = (size_t)nw * ROWLEN;
    const float* px = x   + (size_t)r * ROWLEN + ((size_t)lane << 2);
    float*       po = out + (size_t)r * ROWLEN + ((size_t)lane << 2);

    // ---- prime: load row r (4x dwordx4/lane; imm offsets 0/1/2/3 KB) ----
    float cur[16];
    #pragma unroll
    for (int g = 0; g < 4; ++g) {
        const f32x4 v = *(const f32x4*)(px + (g << 8));
        cur[4*g+0] = v[0]; cur[4*g+1] = v[1];
        cur[4*g+2] = v[2]; cur[4*g+3] = v[3];
    }

    for (;;) {
        // ---- prefetch next row; latency hides under this row's math ----
        const bool has_next = (r + nw < rows);   // wave-uniform
        float nxt[16];
        if (has_next) {
            const float* pn = px + step;
            #pragma unroll
            for (int g = 0; g < 4; ++g) {
                const f32x4 v = *(const f32x4*)(pn + (g << 8));
                nxt[4*g+0] = v[0]; nxt[4*g+1] = v[1];
                nxt[4*g+2] = v[2]; nxt[4*g+3] = v[3];
            }
        }

        // ---- x_int = x/sf via double-float (~CR f32 division), in place ----
        #pragma unroll
        for (int j = 0; j < 16; ++j) {
            const float xx = cur[j];
            const float p  = xx * rh;
            const float e  = __builtin_fmaf(xx, rh, -p);   // exact residual
            cur[j] = p + __builtin_fmaf(xx, rl, e);
        }

        // ---- row max: local tree (15 ops, depth 4) + one DPP chain ----
        float t0 = fmaxf(cur[0], cur[1]),  t1 = fmaxf(cur[2], cur[3]);
        float t2 = fmaxf(cur[4], cur[5]),  t3 = fmaxf(cur[6], cur[7]);
        float t4 = fmaxf(cur[8], cur[9]),  t5 = fmaxf(cur[10], cur[11]);
        float t6 = fmaxf(cur[12], cur[13]),t7 = fmaxf(cur[14], cur[15]);
        t0 = fmaxf(t0, t1); t2 = fmaxf(t2, t3);
        t4 = fmaxf(t4, t5); t6 = fmaxf(t6, t7);
        t0 = fmaxf(t0, t2); t4 = fmaxf(t4, t6);
        const float m = wave_max_dpp(fmaxf(t0, t4));   // -> SGPR broadcast

        // ---- integer exp (f32/int, bit-matching numpy), in place ----
        unsigned usum = 0;    // <= 16 * 3.66e7 < 2^30: exact
        #pragma unroll
        for (int j = 0; j < 16; ++j) {
            float v = cur[j] - m;                 // exact f32 sub
            v = fmaxf(v, clampf);                 // >= -210
            const float qf = floorf(v * invx0f);  // in [0,15]; flips benign
            const int   qi = (int)qf;
            const float rr = v - x0f * qf;        // exact in f32
            const float t  = rr + bfc;
            const float z  = rr * t + cfc;        // two roundings (contract off)
            float ei = floorf(ldexpf(z, 15 - qi)); // pow2 scale exact
            ei = fmaxf(ei, 0.0f);
            cur[j] = ei;
            usum += (unsigned)ei;
        }

        // ---- row sum: lo/hi u32 DPP chains (exact, interleavable) ----
        const unsigned lo = wave_sum_dpp_u32(usum & 0xFFFFu);  // < 2^22
        const unsigned hi = wave_sum_dpp_u32(usum >> 16);      // < 2^20
        const double s = (double)(((unsigned long long)hi << 16) + lo); // exact int

        // ---- row-uniform epilogue constants (f64: once per ROW-WAVE) ----
        const float fac_f = bcast_f32((float)floor(4294967296.0 / s)); // exact int
        const float ath_f = bcast_f32((float)(((double)thrq * s) * (1.0 / 256.0)));

        // ---- quantize + nontemporal store ----
        #pragma unroll
        for (int g = 0; g < 4; ++g) {
            f32x4 o;
            #pragma unroll
            for (int jj = 0; jj < 4; ++jj) {
                const float ei  = cur[4*g+jj];
                const bool  isA = (ei <= ath_f);
                const float t1_ = ei * fac_f;               // bit-matches numpy
                const float t2_ = t1_ * (isA ? invA : invB); // ~f32 division
                float si = floorf(t2_);
                si = fminf(si, isA ? 3.0e38f : 255.0f);     // cap only B path
                o[jj] = si * (isA ? osA : osB);
            }
            __builtin_nontemporal_store(o, (f32x4*)(po + (g << 8)));
        }

        if (!has_next) break;
        r  += nw;
        px += step; po += step;
        #pragma unroll
        for (int j = 0; j < 16; ++j) cur[j] = nxt[j];
    }
}

extern "C" void kernel_launch(void* const* d_in, const int* in_sizes, int n_in,
                              void* d_out, int out_size, void* d_ws, size_t ws_size,
                              hipStream_t stream) {
    const float* x     = (const float*)d_in[0];
    const float* scale = (const float*)d_in[1];
    const float* thr   = (const float*)d_in[2];
    float* out = (float*)d_out;

    const int total = in_sizes[0];        // 2*16*1024*1024
    const int rows  = total / ROWLEN;     // 32768 rows

    const int wave_blocks = (rows + 3) / 4;       // 4 row-waves per block
    const int blocks = wave_blocks < PERSIST_BLOCKS ? wave_blocks : PERSIST_BLOCKS;

    qsplit_int_softmax_kernel<<<dim3(blocks), dim3(TPB), 0, stream>>>(
        x, scale, thr, out, rows);
}